// Round 3
// baseline (184.983 us; speedup 1.0000x reference)
//
#include <hip/hip_runtime.h>
#include <stdint.h>

typedef __bf16 bf16x8 __attribute__((ext_vector_type(8)));
typedef float f32x4 __attribute__((ext_vector_type(4)));
typedef unsigned short u16;

#define NROWS 8192
#define DIM   1024
#define NKT   (DIM / 32)
#define MARGIN 0.3f

// async global->LDS, 16B per lane; LDS dest = wave-uniform base + lane*16
#define GLOAD_LDS16(gp, lp)                                                    \
  __builtin_amdgcn_global_load_lds(                                            \
      (const __attribute__((address_space(1))) void*)(gp),                     \
      (__attribute__((address_space(3))) void*)(lp), 16, 0, 0)

__device__ inline u16 f2bf(float f) {
  union { float f; uint32_t u; } c; c.f = f;
  uint32_t u = c.u;
  return (u16)((u + 0x7fffu + ((u >> 16) & 1u)) >> 16);  // RNE
}

// fp32 [8192*1024] -> bf16 (as u16) ; 8 elems/thread, 16B stores.
// Also zeroes the scalar output (block 0 / thread 0) — saves a launch.
__global__ __launch_bounds__(256) void cvt_f32_bf16(const float* __restrict__ in,
                                                    u16* __restrict__ out,
                                                    float* __restrict__ loss) {
  if (blockIdx.x == 0 && threadIdx.x == 0) loss[0] = 0.0f;
  size_t i = ((size_t)blockIdx.x * 256 + threadIdx.x) * 8;
  float4 v0 = *(const float4*)(in + i);
  float4 v1 = *(const float4*)(in + i + 4);
  union { u16 u[8]; uint4 v; } p;
  p.u[0] = f2bf(v0.x); p.u[1] = f2bf(v0.y); p.u[2] = f2bf(v0.z); p.u[3] = f2bf(v0.w);
  p.u[4] = f2bf(v1.x); p.u[5] = f2bf(v1.y); p.u[6] = f2bf(v1.z); p.u[7] = f2bf(v1.w);
  *(uint4*)(out + i) = p.v;
}

// One block = one 128x128 tile of sim = A*A^T (upper triangle, bi<=bj).
// Double-buffered LDS: prefetch tile kt+1 right after the barrier, compute on
// tile kt -> the compiler's vmcnt(0) drain at the next barrier lands AFTER a
// full compute phase, hiding the global->LDS latency. One barrier per kt.
__global__ __launch_bounds__(256) void gram_loss(const u16* __restrict__ Abf,
                                                 const int* __restrict__ targets,
                                                 float* __restrict__ out) {
  __shared__ u16 As[2][128 * 32];   // 2 x 8 KB, row-major [128][32], NO padding
  __shared__ u16 Bs[2][128 * 32];   // 2 x 8 KB
  __shared__ int tRow[128];
  __shared__ int tCol[128];
  __shared__ float wsum[4];

  // linear block id -> (bi, bj) with 0 <= bi <= bj < 64
  int t = blockIdx.x;
  int bi = (int)(0.5 * (129.0 - sqrt(129.0 * 129.0 - 8.0 * (double)t)));
  if (bi < 0) bi = 0;
  if (bi > 63) bi = 63;
  while (bi < 63 && ((bi + 1) * (129 - (bi + 1))) / 2 <= t) ++bi;
  while (bi > 0 && (bi * (129 - bi)) / 2 > t) --bi;
  int bj = bi + (t - (bi * (129 - bi)) / 2);

  const int iBase = bi * 128;
  const int jBase = bj * 128;

  const int tid  = threadIdx.x;
  const int wave = tid >> 6;
  const int lane = tid & 63;

  if (tid < 128) tRow[tid] = targets[iBase + tid];
  else           tCol[tid - 128] = targets[jBase + tid - 128];

  // staging geometry: 8 chunks of 1KB per tile (16 rows each); wave w owns chunks 2w,2w+1
  const int chunk = wave * 2;
  const int rowInChunk = lane >> 2;        // 0..15
  const int kSub = (lane & 3) * 8;         // 0,8,16,24 (bf16 elems)

  const u16* gA = Abf + (size_t)(iBase + chunk * 16 + rowInChunk) * DIM + kSub;
  const u16* gB = Abf + (size_t)(jBase + chunk * 16 + rowInChunk) * DIM + kSub;
  const int ldsOff = chunk * 512;

  const int m0 = (wave >> 1) * 64;
  const int n0 = (wave & 1) * 64;
  const int fr = lane & 15;
  const int fq = (lane >> 4) * 8;

  f32x4 acc[4][4] = {};

  // prologue: stage tile 0 into buffer 0
  {
    GLOAD_LDS16(gA, &As[0][ldsOff]);
    GLOAD_LDS16(gA + 16 * DIM, &As[0][ldsOff + 512]);
    GLOAD_LDS16(gB, &Bs[0][ldsOff]);
    GLOAD_LDS16(gB + 16 * DIM, &Bs[0][ldsOff + 512]);
  }

  for (int kt = 0; kt < NKT; ++kt) {
    const int cur = kt & 1;
    const int nxt = cur ^ 1;
    // barrier: (a) drains the async loads into buf[cur] (compiler emits
    // vmcnt(0) before s_barrier), (b) guarantees all waves finished reading
    // buf[nxt] in iteration kt-1 -> safe to overwrite it now.
    __syncthreads();
    if (kt + 1 < NKT) {
      const int kOff = (kt + 1) * 32;
      GLOAD_LDS16(gA + kOff, &As[nxt][ldsOff]);
      GLOAD_LDS16(gA + 16 * DIM + kOff, &As[nxt][ldsOff + 512]);
      GLOAD_LDS16(gB + kOff, &Bs[nxt][ldsOff]);
      GLOAD_LDS16(gB + 16 * DIM + kOff, &Bs[nxt][ldsOff + 512]);
    }

    bf16x8 af[4], bfr[4];
#pragma unroll
    for (int mi = 0; mi < 4; ++mi)
      af[mi] = *(const bf16x8*)&As[cur][(m0 + mi * 16 + fr) * 32 + fq];
#pragma unroll
    for (int ni = 0; ni < 4; ++ni)
      bfr[ni] = *(const bf16x8*)&Bs[cur][(n0 + ni * 16 + fr) * 32 + fq];
#pragma unroll
    for (int mi = 0; mi < 4; ++mi)
#pragma unroll
      for (int ni = 0; ni < 4; ++ni)
        acc[mi][ni] = __builtin_amdgcn_mfma_f32_16x16x32_bf16(af[mi], bfr[ni],
                                                              acc[mi][ni], 0, 0, 0);
  }

  // epilogue: C/D layout col = lane&15, row = (lane>>4)*4 + reg  [m89]
  const int col = lane & 15;
  const int rquad = (lane >> 4) * 4;
  float lsum = 0.0f;
#pragma unroll
  for (int ni = 0; ni < 4; ++ni) {
    const int tj = tCol[n0 + ni * 16 + col];
#pragma unroll
    for (int mi = 0; mi < 4; ++mi) {
#pragma unroll
      for (int r = 0; r < 4; ++r) {
        float s = acc[mi][ni][r];
        int ti = tRow[m0 + mi * 16 + rquad + r];
        lsum += (ti == tj) ? (s < 1.0f ? 1.0f - s : 0.0f)
                           : (s > MARGIN ? s : 0.0f);
      }
    }
  }
  if (bi != bj) lsum *= 2.0f;  // symmetric half counted twice

#pragma unroll
  for (int off = 32; off > 0; off >>= 1) lsum += __shfl_down(lsum, off, 64);
  if (lane == 0) wsum[wave] = lsum;
  __syncthreads();
  if (tid == 0)
    atomicAdd(out, (wsum[0] + wsum[1] + wsum[2] + wsum[3]) * (1.0f / (float)NROWS));
}

extern "C" void kernel_launch(void* const* d_in, const int* in_sizes, int n_in,
                              void* d_out, int out_size, void* d_ws, size_t ws_size,
                              hipStream_t stream) {
  const float* x = (const float*)d_in[0];
  const int* targets = (const int*)d_in[1];
  float* out = (float*)d_out;
  u16* xbf = (u16*)d_ws;  // 8192*1024*2 = 16 MiB scratch

  cvt_f32_bf16<<<4096, 256, 0, stream>>>(x, xbf, out);  // 8388608 = 4096*256*8
  gram_loss<<<2080, 256, 0, stream>>>(xbf, targets, out);  // 64*65/2 upper-tri blocks
}

// Round 4
// 177.870 us; speedup vs baseline: 1.0400x; 1.0400x over previous
//
#include <hip/hip_runtime.h>
#include <stdint.h>

typedef __bf16 bf16x8 __attribute__((ext_vector_type(8)));
typedef float f32x4 __attribute__((ext_vector_type(4)));
typedef unsigned short u16;

#define NROWS 8192
#define DIM   1024
#define NKT   (DIM / 32)
#define MARGIN 0.3f

// async global->LDS, 16B per lane; LDS dest = wave-uniform base + lane*16
#define GLOAD_LDS16(gp, lp)                                                    \
  __builtin_amdgcn_global_load_lds(                                            \
      (const __attribute__((address_space(1))) void*)(gp),                     \
      (__attribute__((address_space(3))) void*)(lp), 16, 0, 0)

__device__ inline u16 f2bf(float f) {
  union { float f; uint32_t u; } c; c.f = f;
  uint32_t u = c.u;
  return (u16)((u + 0x7fffu + ((u >> 16) & 1u)) >> 16);  // RNE
}

// fp32 [8192*1024] -> bf16 (as u16) ; 8 elems/thread, 16B stores.
// Also zeroes the scalar output (block 0 / thread 0) — saves a launch.
__global__ __launch_bounds__(256) void cvt_f32_bf16(const float* __restrict__ in,
                                                    u16* __restrict__ out,
                                                    float* __restrict__ loss) {
  if (blockIdx.x == 0 && threadIdx.x == 0) loss[0] = 0.0f;
  size_t i = ((size_t)blockIdx.x * 256 + threadIdx.x) * 8;
  float4 v0 = *(const float4*)(in + i);
  float4 v1 = *(const float4*)(in + i + 4);
  union { u16 u[8]; uint4 v; } p;
  p.u[0] = f2bf(v0.x); p.u[1] = f2bf(v0.y); p.u[2] = f2bf(v0.z); p.u[3] = f2bf(v0.w);
  p.u[4] = f2bf(v1.x); p.u[5] = f2bf(v1.y); p.u[6] = f2bf(v1.z); p.u[7] = f2bf(v1.w);
  *(uint4*)(out + i) = p.v;
}

// One block = one 128x128 tile of sim = A*A^T (upper triangle, bi<=bj).
// Single-buffered (round-1 structure — dbuf regressed, see journal R3).
// __launch_bounds__(256,4): cap regs at 128/wave (64 acc AGPR + <=64 VGPR)
// so 4 blocks/CU fit (round-1 was 140 regs -> 3 blocks/CU, occupancy 28%).
__global__ __launch_bounds__(256, 4) void gram_loss(const u16* __restrict__ Abf,
                                                    const int* __restrict__ targets,
                                                    float* __restrict__ out) {
  __shared__ u16 As[128 * 32];   // 8 KB, row-major [128][32], NO padding
  __shared__ u16 Bs[128 * 32];   // 8 KB
  __shared__ int tRow[128];
  __shared__ int tCol[128];
  __shared__ float wsum[4];

  // linear block id -> (bi, bj) with 0 <= bi <= bj < 64  (fp32 guess + exact fixup)
  int t = blockIdx.x;
  int bi = (int)(0.5f * (129.0f - __builtin_sqrtf(129.0f * 129.0f - 8.0f * (float)t)));
  if (bi < 0) bi = 0;
  if (bi > 63) bi = 63;
  while (bi < 63 && ((bi + 1) * (129 - (bi + 1))) / 2 <= t) ++bi;
  while (bi > 0 && (bi * (129 - bi)) / 2 > t) --bi;
  int bj = bi + (t - (bi * (129 - bi)) / 2);

  const int iBase = bi * 128;
  const int jBase = bj * 128;

  const int tid  = threadIdx.x;
  const int wave = tid >> 6;
  const int lane = tid & 63;

  if (tid < 128) tRow[tid] = targets[iBase + tid];
  else           tCol[tid - 128] = targets[jBase + tid - 128];

  // staging geometry: 8 chunks of 1KB per tile (16 rows each); wave w owns chunks 2w,2w+1
  const int chunk = wave * 2;
  const int rowInChunk = lane >> 2;        // 0..15
  const int kSub = (lane & 3) * 8;         // 0,8,16,24 (bf16 elems)

  const u16* gA = Abf + (size_t)(iBase + chunk * 16 + rowInChunk) * DIM + kSub;
  const u16* gB = Abf + (size_t)(jBase + chunk * 16 + rowInChunk) * DIM + kSub;
  u16* lA = &As[chunk * 512];
  u16* lB = &Bs[chunk * 512];

  const int m0 = (wave >> 1) * 64;
  const int n0 = (wave & 1) * 64;
  const int fr = lane & 15;
  const int fq = (lane >> 4) * 8;

  f32x4 acc[4][4] = {};

  for (int kt = 0; kt < NKT; ++kt) {
    __syncthreads();  // previous tile fully consumed
    const int kOff = kt * 32;
    GLOAD_LDS16(gA + kOff, lA);
    GLOAD_LDS16(gA + 16 * DIM + kOff, lA + 512);
    GLOAD_LDS16(gB + kOff, lB);
    GLOAD_LDS16(gB + 16 * DIM + kOff, lB + 512);
    __syncthreads();  // vmcnt(0) drain + barrier: tile landed

    bf16x8 af[4], bfr[4];
#pragma unroll
    for (int mi = 0; mi < 4; ++mi)
      af[mi] = *(const bf16x8*)&As[(m0 + mi * 16 + fr) * 32 + fq];
#pragma unroll
    for (int ni = 0; ni < 4; ++ni)
      bfr[ni] = *(const bf16x8*)&Bs[(n0 + ni * 16 + fr) * 32 + fq];
#pragma unroll
    for (int mi = 0; mi < 4; ++mi)
#pragma unroll
      for (int ni = 0; ni < 4; ++ni)
        acc[mi][ni] = __builtin_amdgcn_mfma_f32_16x16x32_bf16(af[mi], bfr[ni],
                                                              acc[mi][ni], 0, 0, 0);
  }

  // epilogue: C/D layout col = lane&15, row = (lane>>4)*4 + reg  [m89]
  const int col = lane & 15;
  const int rquad = (lane >> 4) * 4;
  float lsum = 0.0f;
#pragma unroll
  for (int ni = 0; ni < 4; ++ni) {
    const int tj = tCol[n0 + ni * 16 + col];
#pragma unroll
    for (int mi = 0; mi < 4; ++mi) {
#pragma unroll
      for (int r = 0; r < 4; ++r) {
        float s = acc[mi][ni][r];
        int ti = tRow[m0 + mi * 16 + rquad + r];
        lsum += (ti == tj) ? (s < 1.0f ? 1.0f - s : 0.0f)
                           : (s > MARGIN ? s : 0.0f);
      }
    }
  }
  if (bi != bj) lsum *= 2.0f;  // symmetric half counted twice

#pragma unroll
  for (int off = 32; off > 0; off >>= 1) lsum += __shfl_down(lsum, off, 64);
  if (lane == 0) wsum[wave] = lsum;
  __syncthreads();
  if (tid == 0)
    atomicAdd(out, (wsum[0] + wsum[1] + wsum[2] + wsum[3]) * (1.0f / (float)NROWS));
}

extern "C" void kernel_launch(void* const* d_in, const int* in_sizes, int n_in,
                              void* d_out, int out_size, void* d_ws, size_t ws_size,
                              hipStream_t stream) {
  const float* x = (const float*)d_in[0];
  const int* targets = (const int*)d_in[1];
  float* out = (float*)d_out;
  u16* xbf = (u16*)d_ws;  // 8192*1024*2 = 16 MiB scratch

  cvt_f32_bf16<<<4096, 256, 0, stream>>>(x, xbf, out);  // 8388608 = 4096*256*8
  gram_loss<<<2080, 256, 0, stream>>>(xbf, targets, out);  // 64*65/2 upper-tri blocks
}

// Round 5
// 174.675 us; speedup vs baseline: 1.0590x; 1.0183x over previous
//
#include <hip/hip_runtime.h>
#include <stdint.h>

typedef __bf16 bf16x8 __attribute__((ext_vector_type(8)));
typedef float f32x4 __attribute__((ext_vector_type(4)));
typedef unsigned short u16;

#define NROWS 8192
#define DIM   1024
#define NKT   (DIM / 32)
#define MARGIN 0.3f

// async global->LDS, 16B per lane; LDS dest = wave-uniform base + lane*16
#define GLOAD_LDS16(gp, lp)                                                    \
  __builtin_amdgcn_global_load_lds(                                            \
      (const __attribute__((address_space(1))) void*)(gp),                     \
      (__attribute__((address_space(3))) void*)(lp), 16, 0, 0)

__device__ inline u16 f2bf(float f) {
  union { float f; uint32_t u; } c; c.f = f;
  uint32_t u = c.u;
  return (u16)((u + 0x7fffu + ((u >> 16) & 1u)) >> 16);  // RNE
}

// fp32 [8192*1024] -> bf16 (as u16) ; 8 elems/thread, 16B stores.
// Also zeroes the scalar output (block 0 / thread 0) — saves a launch.
__global__ __launch_bounds__(256) void cvt_f32_bf16(const float* __restrict__ in,
                                                    u16* __restrict__ out,
                                                    float* __restrict__ loss) {
  if (blockIdx.x == 0 && threadIdx.x == 0) loss[0] = 0.0f;
  size_t i = ((size_t)blockIdx.x * 256 + threadIdx.x) * 8;
  float4 v0 = *(const float4*)(in + i);
  float4 v1 = *(const float4*)(in + i + 4);
  union { u16 u[8]; uint4 v; } p;
  p.u[0] = f2bf(v0.x); p.u[1] = f2bf(v0.y); p.u[2] = f2bf(v0.z); p.u[3] = f2bf(v0.w);
  p.u[4] = f2bf(v1.x); p.u[5] = f2bf(v1.y); p.u[6] = f2bf(v1.z); p.u[7] = f2bf(v1.w);
  *(uint4*)(out + i) = p.v;
}

// One block = one 128x128 tile of sim = A*A^T (upper triangle, bi<=bj).
// LDS layout is XOR-swizzled to kill the 8-way ds_read_b128 bank conflict
// (R4 counters: exactly 8.0 conflict-cycles per b128 read).
// global_load_lds forces slot = lane*16B, so the swizzle is applied on the
// GLOBAL source address per lane: slot rc*4 + (c ^ ((rc>>2)&3)) holds logical
// col-group c of row rc; readers use the same mapping. Quarter-wave then hits
// each 4-bank group exactly 2x = conflict-free minimum.
__global__ __launch_bounds__(256, 4) void gram_loss(const u16* __restrict__ Abf,
                                                    const int* __restrict__ targets,
                                                    float* __restrict__ out) {
  __shared__ u16 As[128 * 32];   // 8 KB, chunked [8][64 slots][8 u16], swizzled
  __shared__ u16 Bs[128 * 32];   // 8 KB
  __shared__ int tRow[128];
  __shared__ int tCol[128];
  __shared__ float wsum[4];

  // linear block id -> (bi, bj) with 0 <= bi <= bj < 64  (fp32 guess + exact fixup)
  int t = blockIdx.x;
  int bi = (int)(0.5f * (129.0f - __builtin_sqrtf(129.0f * 129.0f - 8.0f * (float)t)));
  if (bi < 0) bi = 0;
  if (bi > 63) bi = 63;
  while (bi < 63 && ((bi + 1) * (129 - (bi + 1))) / 2 <= t) ++bi;
  while (bi > 0 && (bi * (129 - bi)) / 2 > t) --bi;
  int bj = bi + (t - (bi * (129 - bi)) / 2);

  const int iBase = bi * 128;
  const int jBase = bj * 128;

  const int tid  = threadIdx.x;
  const int wave = tid >> 6;
  const int lane = tid & 63;

  if (tid < 128) tRow[tid] = targets[iBase + tid];
  else           tCol[tid - 128] = targets[jBase + tid - 128];

  // staging: 8 chunks of 1KB (16 rows x 64B); wave w owns chunks 2w, 2w+1.
  // lane s is slot s: row-in-chunk = s>>2, GLOBAL col-group = (s&3) ^ ((s>>4)&3)
  const int chunk = wave * 2;
  const int slotRow = lane >> 2;                        // 0..15
  const int kSub = ((lane & 3) ^ ((lane >> 4) & 3)) * 8;  // swizzled source col

  const u16* gA = Abf + (size_t)(iBase + chunk * 16 + slotRow) * DIM + kSub;
  const u16* gB = Abf + (size_t)(jBase + chunk * 16 + slotRow) * DIM + kSub;
  u16* lA = &As[chunk * 512];
  u16* lB = &Bs[chunk * 512];

  const int m0 = (wave >> 1) * 64;
  const int n0 = (wave & 1) * 64;
  const int fr = lane & 15;
  // swizzled read col offset: (h ^ ((fr>>2)&3)) * 8, h = lane>>4
  const int fqs = (((lane >> 4) ^ ((lane >> 2) & 3))) * 8;

  f32x4 acc[4][4] = {};

  for (int kt = 0; kt < NKT; ++kt) {
    __syncthreads();  // previous tile fully consumed
    const int kOff = kt * 32;
    GLOAD_LDS16(gA + kOff, lA);
    GLOAD_LDS16(gA + 16 * DIM + kOff, lA + 512);
    GLOAD_LDS16(gB + kOff, lB);
    GLOAD_LDS16(gB + 16 * DIM + kOff, lB + 512);
    __syncthreads();  // vmcnt(0) drain + barrier: tile landed

    bf16x8 af[4], bfr[4];
#pragma unroll
    for (int mi = 0; mi < 4; ++mi)
      af[mi] = *(const bf16x8*)&As[((m0 >> 4) + mi) * 512 + fr * 32 + fqs];
#pragma unroll
    for (int ni = 0; ni < 4; ++ni)
      bfr[ni] = *(const bf16x8*)&Bs[((n0 >> 4) + ni) * 512 + fr * 32 + fqs];
#pragma unroll
    for (int mi = 0; mi < 4; ++mi)
#pragma unroll
      for (int ni = 0; ni < 4; ++ni)
        acc[mi][ni] = __builtin_amdgcn_mfma_f32_16x16x32_bf16(af[mi], bfr[ni],
                                                              acc[mi][ni], 0, 0, 0);
  }

  // epilogue: C/D layout col = lane&15, row = (lane>>4)*4 + reg  [m89]
  const int col = lane & 15;
  const int rquad = (lane >> 4) * 4;
  float lsum = 0.0f;
#pragma unroll
  for (int ni = 0; ni < 4; ++ni) {
    const int tj = tCol[n0 + ni * 16 + col];
#pragma unroll
    for (int mi = 0; mi < 4; ++mi) {
#pragma unroll
      for (int r = 0; r < 4; ++r) {
        float s = acc[mi][ni][r];
        int ti = tRow[m0 + mi * 16 + rquad + r];
        lsum += (ti == tj) ? (s < 1.0f ? 1.0f - s : 0.0f)
                           : (s > MARGIN ? s : 0.0f);
      }
    }
  }
  if (bi != bj) lsum *= 2.0f;  // symmetric half counted twice

#pragma unroll
  for (int off = 32; off > 0; off >>= 1) lsum += __shfl_down(lsum, off, 64);
  if (lane == 0) wsum[wave] = lsum;
  __syncthreads();
  if (tid == 0)
    atomicAdd(out, (wsum[0] + wsum[1] + wsum[2] + wsum[3]) * (1.0f / (float)NROWS));
}

extern "C" void kernel_launch(void* const* d_in, const int* in_sizes, int n_in,
                              void* d_out, int out_size, void* d_ws, size_t ws_size,
                              hipStream_t stream) {
  const float* x = (const float*)d_in[0];
  const int* targets = (const int*)d_in[1];
  float* out = (float*)d_out;
  u16* xbf = (u16*)d_ws;  // 8192*1024*2 = 16 MiB scratch

  cvt_f32_bf16<<<4096, 256, 0, stream>>>(x, xbf, out);  // 8388608 = 4096*256*8
  gram_loss<<<2080, 256, 0, stream>>>(xbf, targets, out);  // 64*65/2 upper-tri blocks
}